// Round 7
// baseline (1663.336 us; speedup 1.0000x reference)
//
#include <hip/hip_runtime.h>
#include <cstdint>
#include <cstddef>

// Problem constants (match reference)
#define NIT    500
#define GAMMA_ 5.0f
#define CC_    1e-3f
#define KAPPA_ 2.0627128075074256f
#define PEN_   100.0f
#define LR_    0.01f

// d_ws layout: pbuf [128 b][2 dir][2 parity][100] f32 = 204800 B, then flags [256] int.
// TOTAL ~206 KB. r6/r14 post-mortem: both 617 KB layouts failed with garbage-neighbor
// signatures while every <=410 KB layout passed -> treat ws budget as ~512 KB hard.
#define PBUF_BYTES (128*2*2*100*4)
#define FLAG_COUNT 256

// Cross-WG primitives (r11/r13-proven): relaxed SYSTEM-scope atomic load/store ->
// coherence point, no cache-wide maintenance (r11: agent acq/rel wb/inv was a
// ~6us/iter floor), no RMW serialization (r12: RMW polls = HBM atomic storm).
#define VMFENCE() asm volatile("s_waitcnt vmcnt(0)" ::: "memory")
// r21: raw barrier with LDS-only drain. __syncthreads() also drains vmcnt(0),
// which convoys all 12 waves behind the boundary wave's LLC store-acks. The only
// inter-wave data inside the WG is LDS (lgkm); cross-WG ordering is carried by
// the explicit VMFENCE protocol. "memory" clobber pins LDS ops across it.
#define BARRIER() do { asm volatile("s_waitcnt lgkmcnt(0)" ::: "memory"); \
                       __builtin_amdgcn_s_barrier(); } while (0)
__device__ __forceinline__ float sysLoadF(float* p) {
  return __hip_atomic_load(p, __ATOMIC_RELAXED, __HIP_MEMORY_SCOPE_SYSTEM);
}
__device__ __forceinline__ void sysStoreF(float* p, float v) {
  __hip_atomic_store(p, v, __ATOMIC_RELAXED, __HIP_MEMORY_SCOPE_SYSTEM);
}
__device__ __forceinline__ int sysLoadI(int* p) {
  return __hip_atomic_load(p, __ATOMIC_RELAXED, __HIP_MEMORY_SCOPE_SYSTEM);
}
__device__ __forceinline__ void sysStoreI(int* p, int v) {
  __hip_atomic_store(p, v, __ATOMIC_RELAXED, __HIP_MEMORY_SCOPE_SYSTEM);
}
__device__ __forceinline__ int flagRead(int* p, int lane) {
  int f = 0;
  if (lane == 0) f = sysLoadI(p);
  return __builtin_amdgcn_readfirstlane(f);
}
// Intra-WG flag in LDS: workgroup-scope acq/rel = lgkm waits only, no cache ops.
__device__ __forceinline__ int ldsLoadAcq(int* p) {
  return __hip_atomic_load(p, __ATOMIC_ACQUIRE, __HIP_MEMORY_SCOPE_WORKGROUP);
}
__device__ __forceinline__ void ldsStoreRel(int* p, int v) {
  __hip_atomic_store(p, v, __ATOMIC_RELEASE, __HIP_MEMORY_SCOPE_WORKGROUP);
}

__device__ __forceinline__ float rdlane(float v, int lane) {
  return __int_as_float(__builtin_amdgcn_readlane(__float_as_int(v), lane));
}

// Wave64 sum via DPP, total broadcast from lane 63. Verified r5..r13.
__device__ __forceinline__ float wred64(float x) {
  int t;
  t = __builtin_amdgcn_update_dpp(0, __float_as_int(x), 0x111, 0xf, 0xf, true); x += __int_as_float(t);
  t = __builtin_amdgcn_update_dpp(0, __float_as_int(x), 0x112, 0xf, 0xf, true); x += __int_as_float(t);
  t = __builtin_amdgcn_update_dpp(0, __float_as_int(x), 0x114, 0xf, 0xf, true); x += __int_as_float(t);
  t = __builtin_amdgcn_update_dpp(0, __float_as_int(x), 0x118, 0xf, 0xf, true); x += __int_as_float(t);
  t = __builtin_amdgcn_update_dpp(0, __float_as_int(x), 0x142, 0xa, 0xf, true); x += __int_as_float(t);
  t = __builtin_amdgcn_update_dpp(0, __float_as_int(x), 0x143, 0xc, 0xf, true); x += __int_as_float(t);
  return rdlane(x, 63);
}

// r22 = r21 (best: 1641.6us) + BALLOT-COUNT MICHELOT.
// r20 established the kernel is A-wave-instruction-proportional (+13% instrs ->
// +12% time). Biggest removable line item: the SECOND wred64 per Michelot pass,
// which only counts a predicate. v_cmp already yields the 64-bit mask, so
// Cnt = popc(ballot(c0)) + popc(ballot(c1)): compare shared with the sum's
// select, ballot reads vcc, popcount is SALU (no VALU issue slot). A 0/1-float
// sum is exact == popcount -> Cnt bit-identical -> theta/support/w bit-identical
// -> absmax must stay exactly 0.0001220703. Saves ~14 VALU instrs/pass and one
// serial DPP chain per pass (~70-90 instrs of A's ~1000/iter).
// Post-mortems retained: r16 flag-desync +4%; r17 SIMD remap flat; r18/r19
// 384-thr WGs serialized (occ 17%); r20 full-support start +12%.
// S constant-indexed only (r9: runtime index -> scratch spill -> 19.6 GB FETCH).
__global__ __launch_bounds__(768, 1) void mpo_solver(
    const float* __restrict__ mu, const float* __restrict__ L,
    const float* __restrict__ wprev, const float* __restrict__ climit,
    float* __restrict__ out, float* __restrict__ pbuf, int* __restrict__ flags)
{
  const int tid  = threadIdx.x;
  const int lane = tid & 63;
  const int wave = __builtin_amdgcn_readfirstlane(tid >> 6);  // 0..11
  const int j    = wave >> 1;       // local head 0..5
  const int sec  = wave & 1;        // 0 = rows 0-49 + post, 1 = rows 50-99
  const int bid  = blockIdx.x;
  const int b    = bid & 127;
  const int half = bid >> 7;        // 0: heads 0-5, 1: heads 6-11
  const int h    = half * 6 + j;    // global head
  const int bh   = b * 12 + h;

  __shared__ float wbuf[2][6][100];   // double-buffered w per head
  __shared__ float ybuf[6][100];      // y rows 50-99 per head (B-wave's half)
  __shared__ float nbuf[100];         // delegated cross-WG neighbor w (one boundary head/WG)
  __shared__ int   nflag;             // nbuf holds iter-k data -> k

  const float* Lb = L + (size_t)bh * 10000;

  // ---------- Phase 0: SYRK. Lane owns row r of S = L L^T (fp32 regs/AGPRs). ----------
  float S[100];
#pragma unroll
  for (int c = 0; c < 100; ++c) S[c] = 0.f;
  const int r = sec * 50 + lane;      // valid row iff lane < 50
  if (lane < 50) {
#pragma unroll 1
    for (int mc = 0; mc < 25; ++mc) {
      float4 lr = *(const float4*)(Lb + r * 100 + mc * 4);
#pragma unroll
      for (int c = 0; c < 100; ++c) {
        const float* Lc = Lb + c * 100 + mc * 4;   // wave-uniform -> scalar loads
        S[c] = fmaf(lr.x, Lc[0], fmaf(lr.y, Lc[1], fmaf(lr.z, Lc[2], fmaf(lr.w, Lc[3], S[c]))));
      }
    }
  }

  const bool val1 = (lane < 36);
  float mu0 = mu[(size_t)bh * 100 + lane];
  float mu1 = val1 ? mu[(size_t)bh * 100 + 64 + lane] : 0.f;
  float wp0 = wprev[b * 100 + lane];
  float wp1 = val1 ? wprev[b * 100 + 64 + lane] : 0.f;
  float lim = climit[b];

  float w0 = wp0, w1 = wp1;           // post wave's iterate (n = lane, 64+lane)

  if (sec == 0) {
    wbuf[0][j][lane] = wp0;
    if (val1) wbuf[0][j][64 + lane] = wp1;
  }
  if (tid == 0) nflag = 0;
  __syncthreads();                    // init barrier (full semantics, once)

  const bool hasNext = (h < 11);
  const bool isPubL  = (half == 0) && (j == 5);  // boundary head: publishes 5, consumes 6
  const bool isPubH  = (half == 1) && (j == 0);  // boundary head: publishes 6, consumes 5
  const bool isBnd   = isPubL || isPubH;
  const int  flagPub = isPubL ? (b * 2 + 0) : (b * 2 + 1);
  const int  flagCon = isPubL ? (b * 2 + 1) : (b * 2 + 0);
  bool dead = false;
  float thp = -3.0e38f;               // warm Michelot seed; k=0 -> full support

  for (int k = 0; k < NIT; ++k) {
    const int p = k & 1;

    // ---- deferred cross-WG flag publish for w^k (data stores issued at end of
    // post(k-1); acks retired during barrier-2 -> fence near-free; flag store
    // flies under the matvec, never between the barriers).
    if (sec == 0 && isBnd && k > 0) {
      VMFENCE();
      if (lane == 0) sysStoreI(&flags[flagPub], k);
    }

    // ret depends only on w^k (regs) and mu -> hoist its DPP chain above the
    // matvec so the latency hides under the FMA stream (value bitwise identical).
    float ret = 0.f;
    if (sec == 0) ret = wred64(fmaf(mu0, w0, mu1 * w1));

    // ---------- matvec y = S * w_k: wave-uniform ds_read_b128 broadcast ----------
    float yloc;
    {
      float a0 = 0.f, a1 = 0.f, a2 = 0.f, a3 = 0.f;
      const float* wrow = wbuf[p][j];
#pragma unroll
      for (int q = 0; q < 25; ++q) {
        float4 wq = *(const float4*)(wrow + q * 4);
        a0 = fmaf(wq.x, S[q * 4 + 0], a0);
        a1 = fmaf(wq.y, S[q * 4 + 1], a1);
        a2 = fmaf(wq.z, S[q * 4 + 2], a2);
        a3 = fmaf(wq.w, S[q * 4 + 3], a3);
      }
      yloc = (a0 + a2) + (a1 + a3);
      if (sec == 1 && lane < 50) ybuf[j][50 + lane] = yloc;  // only B publishes its half
    }
    BARRIER();

    // ================= post window =================
    if (sec == 1) {
      // ---- B wave of the boundary head: delegated cross-WG read (otherwise idle) ----
      if (isBnd && k > 0) {
        if (!dead) {
          long guard = 0;
          while (flagRead(&flags[flagCon], lane) < k) {
            __builtin_amdgcn_s_sleep(1);
            if (++guard > (1L << 18)) { dead = true; break; }
          }
        }
        // two-phase: data issued only after flag>=k observed (producer fenced
        // data before flag -> flag visible implies data visible)
        float* src = pbuf + ((size_t)flagCon * 2 + (k & 1)) * 100;
        nbuf[lane] = sysLoadF(&src[lane]);
        if (val1) nbuf[64 + lane] = sysLoadF(&src[64 + lane]);
        ldsStoreRel(&nflag, k);   // release covers the nbuf LDS writes
      }
    } else {
      // ---------------- A wave: post ----------------
      float y0 = (lane < 50) ? yloc : ybuf[j][lane];
      float y1 = val1 ? ybuf[j][64 + lane] : 0.f;

      float s2  = wred64(fmaf(y0, w0, y1 * w1));
      float sigma = sqrtf(s2 + 1e-12f);
      float z     = KAPPA_ * sigma - ret - lim;
      float act   = (z > 0.f) ? 1.f : 0.f;
      float cY    = 2.f * GAMMA_ + act * (PEN_ * KAPPA_ / sigma);
      float cM    = -(1.f + act * PEN_);

      // neighbor w (iterate k exactly — Jacobi, matches reference)
      float wl0, wl1, wn0 = 0.f, wn1 = 0.f;
      if (j == 0) {
        if (half == 0 || k == 0) { wl0 = wp0; wl1 = wp1; }
        else {
          if (!dead) {
            long guard = 0;
            while (ldsLoadAcq(&nflag) < k) {
              __builtin_amdgcn_s_sleep(1);
              if (++guard > (1L << 18)) { dead = true; break; }
            }
          }
          wl0 = nbuf[lane];
          wl1 = val1 ? nbuf[64 + lane] : 0.f;
        }
      } else { wl0 = wbuf[p][j - 1][lane]; wl1 = val1 ? wbuf[p][j - 1][64 + lane] : 0.f; }
      if (hasNext) {
        if (j == 5) {  // half==0 boundary: next is head 6 (delegated)
          if (k == 0) { wn0 = wp0; wn1 = wp1; }
          else {
            if (!dead) {
              long guard = 0;
              while (ldsLoadAcq(&nflag) < k) {
                __builtin_amdgcn_s_sleep(1);
                if (++guard > (1L << 18)) { dead = true; break; }
              }
            }
            wn0 = nbuf[lane];
            wn1 = val1 ? nbuf[64 + lane] : 0.f;
          }
        } else { wn0 = wbuf[p][j + 1][lane]; wn1 = val1 ? wbuf[p][j + 1][64 + lane] : 0.f; }
      }

      float dw0 = w0 - wl0;
      float g0  = fmaf(cM, mu0, cY * y0) + CC_ * (dw0 * rsqrtf(fmaf(dw0, dw0, 1e-10f)));
      if (hasNext) { float dn0 = wn0 - w0; g0 -= CC_ * (dn0 * rsqrtf(fmaf(dn0, dn0, 1e-10f))); }
      float v0 = fmaf(-LR_, g0, w0);
      float v1 = 0.f;
      if (val1) {
        float dw1 = w1 - wl1;
        float g1  = fmaf(cM, mu1, cY * y1) + CC_ * (dw1 * rsqrtf(fmaf(dw1, dw1, 1e-10f)));
        if (hasNext) { float dn1 = wn1 - w1; g1 -= CC_ * (dn1 * rsqrtf(fmaf(dn1, dn1, 1e-10f))); }
        v1 = fmaf(-LR_, g1, w1);
      }

      // ---- Michelot projection, warm-started, BALLOT-COUNT (r22).
      // Support count via ballot+popcount (SALU) instead of a second wred64:
      // 0/1-float sums are exact, popcount gives the same integer -> Cnt, theta,
      // support trajectory and w are bit-identical to r21's numerics.
      float a1m = val1 ? 1.f : 0.f;
      {
        bool c0 = (v0 > thp);
        bool c1 = (val1 && (v1 > thp));
        float Ssum = wred64((c0 ? v0 : 0.f) + (c1 ? v1 : 0.f));
        float Cnt  = (float)(__popcll(__ballot(c0)) + __popcll(__ballot(c1)));
        if (Cnt < 0.5f) { Ssum = wred64(v0 + a1m * v1); Cnt = 100.f; }
        float theta = (Ssum - 1.f) / Cnt;
        for (int it = 0; it < 112; ++it) {
          bool b0 = (v0 > theta);
          bool b1 = (val1 && (v1 > theta));
          float ns = wred64((b0 ? v0 : 0.f) + (b1 ? v1 : 0.f));
          float nc = (float)(__popcll(__ballot(b0)) + __popcll(__ballot(b1)));
          if (nc == Cnt && ns == Ssum) break;
          if (it == 7) {  // warm-start may cycle: reset to full support (monotone)
            ns = wred64(v0 + a1m * v1);
            nc = 100.f;
          }
          Ssum = ns; Cnt = nc;
          theta = (Ssum - 1.f) / Cnt;
        }
        thp = theta;
        w0 = fmaxf(v0 - theta, 0.f);
        w1 = val1 ? fmaxf(v1 - theta, 0.f) : 0.f;
      }

      wbuf[1 - p][j][lane] = w0;
      if (val1) wbuf[1 - p][j][64 + lane] = w1;

      // ---- cross-WG publish, DATA ONLY (boundary A): stores fly through
      // barrier-2 (raw barrier no longer drains vmcnt); fence+flag happen at
      // the start of iteration k+1.
      if (isBnd) {
        float* dst = pbuf + ((size_t)flagPub * 2 + ((k + 1) & 1)) * 100;
        sysStoreF(&dst[lane], w0);
        if (val1) sysStoreF(&dst[64 + lane], w1);
      }
    }
    BARRIER();
  }

  if (sec == 0) {
    float* o = out + (size_t)bh * 100;
    o[lane] = w0;
    if (val1) o[64 + lane] = w1;
  }
}

extern "C" void kernel_launch(void* const* d_in, const int* in_sizes, int n_in,
                              void* d_out, int out_size, void* d_ws, size_t ws_size,
                              hipStream_t stream) {
  const float* mu = (const float*)d_in[0];
  const float* L  = (const float*)d_in[1];
  const float* wp = (const float*)d_in[2];
  const float* cl = (const float*)d_in[3];
  float* pbuf  = (float*)d_ws;
  int*   flags = (int*)((char*)d_ws + PBUF_BYTES);
  hipMemsetAsync(flags, 0, FLAG_COUNT * sizeof(int), stream);
  hipLaunchKernelGGL(mpo_solver, dim3(256), dim3(768), 0, stream,
                     mu, L, wp, cl, (float*)d_out, pbuf, flags);
}